// Round 5
// baseline (148.838 us; speedup 1.0000x reference)
//
#include <hip/hip_runtime.h>
#include <math.h>

#define DELTA_V 0.5f
#define DELTA_D 3.0f
#define P_REG   0.001f
#define TPB     256
#define NVMAX   36

// Balanced grid: binary 4 iters x 48 B = instance 2 iters x 96 B = 49 KB/block.
// Exact fit at n4 = 131072: 128*256*4 = 256*256*2 = 131072.
#define BPSB 128
#define BPSI 256
#define NBLK (4 * BPSB + 4 * BPSI)   // 1536 blocks = 6/CU, 24 waves/CU

// float-offset ws layout; every word read is written first (poison-safe).
#define P1_OFF    0                             // [NVMAX][NBLK] transposed pass1 partials
#define LBL_OFF   (P1_OFF + NVMAX * NBLK)       // packed uchar labels: 8*MN bytes

// ---------------- Pass 1: per-label counts/sums + label re-pack + out zero ----------------
template<int K, int D>
__device__ void pass1_body(const float* __restrict__ pred,   // [D][MN] this slice
                           const int*  __restrict__ labels,  // [MN]
                           float* __restrict__ ws,
                           uchar4* __restrict__ lblPack,     // [n4] this slice's packed labels
                           int n4, int bx, int stride, int bid,
                           float (*lredW)[NVMAX]) {
    constexpr int NV = K * (D + 1);
    const float4* pred4 = (const float4*)pred;
    const int4*   lab4  = (const int4*)labels;

    float acc[K][D + 1];
    #pragma unroll
    for (int k = 0; k < K; ++k)
        #pragma unroll
        for (int j = 0; j <= D; ++j) acc[k][j] = 0.f;

    for (int i = bx * TPB + threadIdx.x; i < n4; i += stride) {
        int4 lv = lab4[i];
        int labs[4] = {lv.x, lv.y, lv.z, lv.w};
        lblPack[i] = make_uchar4((unsigned char)lv.x, (unsigned char)lv.y,
                                 (unsigned char)lv.z, (unsigned char)lv.w);
        float4 xv[D];
        #pragma unroll
        for (int d = 0; d < D; ++d) xv[d] = pred4[(size_t)d * n4 + i];
        const float* xs = (const float*)&xv[0];   // xs[d*4 + c]
        #pragma unroll
        for (int c = 0; c < 4; ++c) {
            const int lab = labs[c];
            #pragma unroll
            for (int k = 0; k < K; ++k) {
                const float ind = (lab == k) ? 1.f : 0.f;
                acc[k][D] += ind;
                #pragma unroll
                for (int d = 0; d < D; ++d)
                    acc[k][d] = fmaf(ind, xs[d * 4 + c], acc[k][d]);
            }
        }
    }

    const int wave = threadIdx.x >> 6, lane = threadIdx.x & 63;
    #pragma unroll
    for (int k = 0; k < K; ++k) {
        #pragma unroll
        for (int j = 0; j <= D; ++j) {
            float v = acc[k][j];
            for (int off = 32; off > 0; off >>= 1) v += __shfl_down(v, off);
            if (lane == 0) lredW[wave][k * (D + 1) + j] = v;
        }
    }
    __syncthreads();
    if (threadIdx.x < NV) {
        const int t = threadIdx.x;
        ws[P1_OFF + (size_t)t * NBLK + bid] =   // transposed: row t, column bid
            lredW[0][t] + lredW[1][t] + lredW[2][t] + lredW[3][t];
    }
}

__global__ __launch_bounds__(TPB)
void pass1_k(const float* __restrict__ bl, const int* __restrict__ bL,
             const float* __restrict__ il, const int* __restrict__ iL,
             float* __restrict__ ws, float* __restrict__ out, int MN) {
    // zero the atomic accumulators for pass2 (kernel-boundary release -> visible)
    if (blockIdx.x == 0 && threadIdx.x == 0) { out[0] = 0.f; out[1] = 0.f; }

    __shared__ float lredW[4][NVMAX];
    const int bid = blockIdx.x, n4 = MN >> 2;
    uchar4* lblBase = (uchar4*)(ws + LBL_OFF);
    if (bid < 4 * BPSB) {
        const int s = bid / BPSB, bx = bid - s * BPSB;
        pass1_body<2, 2>(bl + (size_t)s * 2 * MN, bL + (size_t)s * MN,
                         ws, lblBase + (size_t)s * n4, n4, bx, BPSB * TPB, bid, lredW);
    } else {
        const int r = bid - 4 * BPSB;
        const int si = r / BPSI, bx = r - si * BPSI;
        pass1_body<6, 5>(il + (size_t)si * 5 * MN, iL + (size_t)si * MN,
                         ws, lblBase + (size_t)(4 + si) * n4, n4, bx, BPSI * TPB, bid, lredW);
    }
}

// ---------------- Pass 2: parallel means-reduce + hinged variance + atomic finish ----------------
template<int K, int D, int NBP>
__device__ void pass2_slice(const float* __restrict__ pred,
                            const uchar4* __restrict__ lblPack,
                            const float* __restrict__ ws, float* __restrict__ out,
                            const int s, const int bx, const int bid, const int n4) {
    constexpr int NV = K * (D + 1);
    constexpr int G  = TPB / NV;          // 42 for (2,2), 7 for (6,5)
    __shared__ float red[G][NV];
    __shared__ float muS[30];
    __shared__ float cntS[6];
    __shared__ float lredW[4][6];
    const int t = threadIdx.x;
    const int sliceBase = bid - bx;

    // parallel redundant reduce of this slice's transposed P1 partials.
    // Fixed (g, then j stride-G) order -> bitwise-identical means in every
    // block of the slice, which is all correctness requires.
    if (t < G * NV) {
        const int g = t / NV, v = t - g * NV;
        const float* P = ws + P1_OFF + (size_t)v * NBLK + sliceBase;
        float sm = 0.f;
        for (int j = g; j < NBP; j += G) sm += P[j];
        red[g][v] = sm;
    }
    __syncthreads();
    if (t < NV) {
        float sm = 0.f;
        #pragma unroll
        for (int g = 0; g < G; ++g) sm += red[g][t];
        const int k = t / (D + 1), jj = t - k * (D + 1);
        if (jj == D) cntS[k] = sm;
        else         red[0][t] = sm;     // stash sums for the mean divide
    }
    __syncthreads();
    if (t < NV) {
        const int k = t / (D + 1), jj = t - k * (D + 1);
        if (jj < D) muS[k * D + jj] = red[0][t] / cntS[k];
    }
    __syncthreads();

    // bx==0 thread 0 keeps (dist + reg) scalar in a register for the atomic at the end
    float ldr = 0.f;
    if (bx == 0 && t == 0) {
        float l_dist = 0.f, l_reg = 0.f;
        for (int i = 0; i < K; ++i) {
            float n2 = 0.f;
            for (int d = 0; d < D; ++d) n2 += muS[i * D + d] * muS[i * D + d];
            l_reg += sqrtf(n2);
            for (int j = 0; j < K; ++j) {
                if (i == j) continue;
                float sq = 0.f;
                for (int d = 0; d < D; ++d) {
                    const float df = muS[i * D + d] - muS[j * D + d];
                    sq += df * df;
                }
                const float dn = fmaxf(2.f * DELTA_D - sqrtf(sq), 0.f);
                l_dist += dn * dn;
            }
        }
        ldr = l_dist / (float)(K * (K - 1)) + P_REG * (l_reg / (float)K);
    }

    // streaming hinged-variance pass: packed 1-byte labels (4 B/quad vs 16 B)
    const float4* pred4 = (const float4*)pred;

    float acc[K];
    #pragma unroll
    for (int k = 0; k < K; ++k) acc[k] = 0.f;

    const int stride = NBP * TPB;
    for (int i = bx * TPB + t; i < n4; i += stride) {
        const uchar4 lq = lblPack[i];
        int labs[4] = {lq.x, lq.y, lq.z, lq.w};
        float4 xv[D];
        #pragma unroll
        for (int d = 0; d < D; ++d) xv[d] = pred4[(size_t)d * n4 + i];
        const float* xs = (const float*)&xv[0];
        #pragma unroll
        for (int c = 0; c < 4; ++c) {
            const int lab = labs[c];
            float sq = 0.f;
            #pragma unroll
            for (int d = 0; d < D; ++d) {
                const float df = muS[lab * D + d] - xs[d * 4 + c];
                sq = fmaf(df, df, sq);
            }
            const float h = fmaxf(sqrtf(sq) - DELTA_V, 0.f);
            const float h2 = h * h;
            #pragma unroll
            for (int k = 0; k < K; ++k)
                acc[k] += (lab == k) ? h2 : 0.f;
        }
    }

    const int wave = t >> 6, lane = t & 63;
    #pragma unroll
    for (int k = 0; k < K; ++k) {
        float v = acc[k];
        for (int off = 32; off > 0; off >>= 1) v += __shfl_down(v, off);
        if (lane == 0) lredW[wave][k] = v;
    }
    __syncthreads();

    // per-block normalized contribution, one float atomicAdd per block
    if (t == 0) {
        float contrib = 0.f;
        #pragma unroll
        for (int k = 0; k < K; ++k) {
            const float sk = lredW[0][k] + lredW[1][k] + lredW[2][k] + lredW[3][k];
            contrib += sk / cntS[k];
        }
        contrib *= 0.25f / (float)K;          // /K (label mean), /4 (batch mean)
        contrib += 0.25f * ldr;               // dist+reg (nonzero only for bx==0)
        atomicAdd(out + ((s < 4) ? 0 : 1), contrib);
    }
}

__global__ __launch_bounds__(TPB)
void pass2_k(const float* __restrict__ bl, const float* __restrict__ il,
             const float* __restrict__ ws, float* __restrict__ out, int MN) {
    const int bid = blockIdx.x, n4 = MN >> 2;
    const uchar4* lblBase = (const uchar4*)(ws + LBL_OFF);
    if (bid < 4 * BPSB) {
        const int s = bid / BPSB, bx = bid - s * BPSB;
        pass2_slice<2, 2, BPSB>(bl + (size_t)s * 2 * MN, lblBase + (size_t)s * n4,
                                ws, out, s, bx, bid, n4);
    } else {
        const int r = bid - 4 * BPSB;
        const int si = r / BPSI, bx = r - si * BPSI;
        pass2_slice<6, 5, BPSI>(il + (size_t)si * 5 * MN, lblBase + (size_t)(4 + si) * n4,
                                ws, out, 4 + si, bx, bid, n4);
    }
}

// ---------------- launch: two plain (graph-friendly) dispatches ----------------
extern "C" void kernel_launch(void* const* d_in, const int* in_sizes, int n_in,
                              void* d_out, int out_size, void* d_ws, size_t ws_size,
                              hipStream_t stream) {
    const float* bl = (const float*)d_in[0];
    const int*   bL = (const int*)d_in[1];
    const float* il = (const float*)d_in[2];
    const int*   iL = (const int*)d_in[3];
    float* ws  = (float*)d_ws;
    float* out = (float*)d_out;

    const int B  = 4;
    const int MN = in_sizes[1] / B;   // 524288

    pass1_k<<<dim3(NBLK), dim3(TPB), 0, stream>>>(bl, bL, il, iL, ws, out, MN);
    pass2_k<<<dim3(NBLK), dim3(TPB), 0, stream>>>(bl, il, ws, out, MN);
}

// Round 6
// 144.873 us; speedup vs baseline: 1.0274x; 1.0274x over previous
//
#include <hip/hip_runtime.h>
#include <math.h>

#define DELTA_V 0.5f
#define DELTA_D 3.0f
#define P_REG   0.001f
#define TPB     256
#define NVMAX   36

// Balanced grid: binary 4 iters x 48 B = instance 2 iters x 96 B = 49 KB/block.
// Exact fit at n4 = 131072: 128*256*4 = 256*256*2 = 131072.
#define BPSB 128
#define BPSI 256
#define NBLK (4 * BPSB + 4 * BPSI)   // 1536 blocks = 6/CU, 24 waves/CU
#define NBLKB (4 * BPSB)             // 512 binary blocks

// float-offset ws layout; every word read is written first (poison-safe).
#define P1_OFF    0                             // [NVMAX][NBLK] transposed pass1 partials
#define LBL_OFF   (P1_OFF + NVMAX * NBLK)       // packed uchar labels: 8*MN bytes
#define CTB_OFF   (LBL_OFF + 2 * 524288)        // [NBLK] per-block normalized contributions
#define LDR_OFF   (CTB_OFF + NBLK)              // [8] per-slice dist+reg scalars

// ---------------- Pass 1: per-label counts/sums + label re-pack ----------------
template<int K, int D>
__device__ void pass1_body(const float* __restrict__ pred,   // [D][MN] this slice
                           const int*  __restrict__ labels,  // [MN]
                           float* __restrict__ ws,
                           uchar4* __restrict__ lblPack,     // [n4] this slice's packed labels
                           int n4, int bx, int stride, int bid,
                           float (*lredW)[NVMAX]) {
    constexpr int NV = K * (D + 1);
    const float4* pred4 = (const float4*)pred;
    const int4*   lab4  = (const int4*)labels;

    float acc[K][D + 1];
    #pragma unroll
    for (int k = 0; k < K; ++k)
        #pragma unroll
        for (int j = 0; j <= D; ++j) acc[k][j] = 0.f;

    for (int i = bx * TPB + threadIdx.x; i < n4; i += stride) {
        int4 lv = lab4[i];
        int labs[4] = {lv.x, lv.y, lv.z, lv.w};
        lblPack[i] = make_uchar4((unsigned char)lv.x, (unsigned char)lv.y,
                                 (unsigned char)lv.z, (unsigned char)lv.w);
        float4 xv[D];
        #pragma unroll
        for (int d = 0; d < D; ++d) xv[d] = pred4[(size_t)d * n4 + i];
        const float* xs = (const float*)&xv[0];   // xs[d*4 + c]
        #pragma unroll
        for (int c = 0; c < 4; ++c) {
            const int lab = labs[c];
            #pragma unroll
            for (int k = 0; k < K; ++k) {
                const float ind = (lab == k) ? 1.f : 0.f;
                acc[k][D] += ind;
                #pragma unroll
                for (int d = 0; d < D; ++d)
                    acc[k][d] = fmaf(ind, xs[d * 4 + c], acc[k][d]);
            }
        }
    }

    const int wave = threadIdx.x >> 6, lane = threadIdx.x & 63;
    #pragma unroll
    for (int k = 0; k < K; ++k) {
        #pragma unroll
        for (int j = 0; j <= D; ++j) {
            float v = acc[k][j];
            for (int off = 32; off > 0; off >>= 1) v += __shfl_down(v, off);
            if (lane == 0) lredW[wave][k * (D + 1) + j] = v;
        }
    }
    __syncthreads();
    if (threadIdx.x < NV) {
        const int t = threadIdx.x;
        ws[P1_OFF + (size_t)t * NBLK + bid] =   // transposed: row t, column bid
            lredW[0][t] + lredW[1][t] + lredW[2][t] + lredW[3][t];
    }
}

__global__ __launch_bounds__(TPB)
void pass1_k(const float* __restrict__ bl, const int* __restrict__ bL,
             const float* __restrict__ il, const int* __restrict__ iL,
             float* __restrict__ ws, int MN) {
    __shared__ float lredW[4][NVMAX];
    const int bid = blockIdx.x, n4 = MN >> 2;
    uchar4* lblBase = (uchar4*)(ws + LBL_OFF);
    if (bid < NBLKB) {
        const int s = bid / BPSB, bx = bid - s * BPSB;
        pass1_body<2, 2>(bl + (size_t)s * 2 * MN, bL + (size_t)s * MN,
                         ws, lblBase + (size_t)s * n4, n4, bx, BPSB * TPB, bid, lredW);
    } else {
        const int r = bid - NBLKB;
        const int si = r / BPSI, bx = r - si * BPSI;
        pass1_body<6, 5>(il + (size_t)si * 5 * MN, iL + (size_t)si * MN,
                         ws, lblBase + (size_t)(4 + si) * n4, n4, bx, BPSI * TPB, bid, lredW);
    }
}

// ---------------- Pass 2: parallel means-reduce + hinged variance + plain-store finish ----------------
template<int K, int D, int NBP>
__device__ void pass2_slice(const float* __restrict__ pred,
                            const uchar4* __restrict__ lblPack,
                            float* __restrict__ ws,
                            const int s, const int bx, const int bid, const int n4) {
    constexpr int NV = K * (D + 1);
    constexpr int G  = TPB / NV;          // 42 for (2,2), 7 for (6,5)
    __shared__ float red[G][NV];
    __shared__ float muS[30];
    __shared__ float cntS[6];
    __shared__ float lredW[4][6];
    const int t = threadIdx.x;
    const int sliceBase = bid - bx;

    // parallel redundant reduce of this slice's transposed P1 partials.
    // Fixed (g, then j stride-G) order -> bitwise-identical means in every
    // block of the slice, which is all correctness requires.
    if (t < G * NV) {
        const int g = t / NV, v = t - g * NV;
        const float* P = ws + P1_OFF + (size_t)v * NBLK + sliceBase;
        float sm = 0.f;
        for (int j = g; j < NBP; j += G) sm += P[j];
        red[g][v] = sm;
    }
    __syncthreads();
    if (t < NV) {
        float sm = 0.f;
        #pragma unroll
        for (int g = 0; g < G; ++g) sm += red[g][t];
        const int k = t / (D + 1), jj = t - k * (D + 1);
        if (jj == D) cntS[k] = sm;
        else         red[0][t] = sm;     // stash sums for the mean divide
    }
    __syncthreads();
    if (t < NV) {
        const int k = t / (D + 1), jj = t - k * (D + 1);
        if (jj < D) muS[k * D + jj] = red[0][t] / cntS[k];
    }
    __syncthreads();

    // bx==0 thread 0 publishes the (dist + reg) scalar for this slice
    if (bx == 0 && t == 0) {
        float l_dist = 0.f, l_reg = 0.f;
        for (int i = 0; i < K; ++i) {
            float n2 = 0.f;
            for (int d = 0; d < D; ++d) n2 += muS[i * D + d] * muS[i * D + d];
            l_reg += sqrtf(n2);
            for (int j = 0; j < K; ++j) {
                if (i == j) continue;
                float sq = 0.f;
                for (int d = 0; d < D; ++d) {
                    const float df = muS[i * D + d] - muS[j * D + d];
                    sq += df * df;
                }
                const float dn = fmaxf(2.f * DELTA_D - sqrtf(sq), 0.f);
                l_dist += dn * dn;
            }
        }
        ws[LDR_OFF + s] =
            l_dist / (float)(K * (K - 1)) + P_REG * (l_reg / (float)K);
    }

    // streaming hinged-variance pass: packed 1-byte labels (4 B/quad vs 16 B)
    const float4* pred4 = (const float4*)pred;

    float acc[K];
    #pragma unroll
    for (int k = 0; k < K; ++k) acc[k] = 0.f;

    const int stride = NBP * TPB;
    for (int i = bx * TPB + t; i < n4; i += stride) {
        const uchar4 lq = lblPack[i];
        int labs[4] = {lq.x, lq.y, lq.z, lq.w};
        float4 xv[D];
        #pragma unroll
        for (int d = 0; d < D; ++d) xv[d] = pred4[(size_t)d * n4 + i];
        const float* xs = (const float*)&xv[0];
        #pragma unroll
        for (int c = 0; c < 4; ++c) {
            const int lab = labs[c];
            float sq = 0.f;
            #pragma unroll
            for (int d = 0; d < D; ++d) {
                const float df = muS[lab * D + d] - xs[d * 4 + c];
                sq = fmaf(df, df, sq);
            }
            const float h = fmaxf(sqrtf(sq) - DELTA_V, 0.f);
            const float h2 = h * h;
            #pragma unroll
            for (int k = 0; k < K; ++k)
                acc[k] += (lab == k) ? h2 : 0.f;
        }
    }

    const int wave = t >> 6, lane = t & 63;
    #pragma unroll
    for (int k = 0; k < K; ++k) {
        float v = acc[k];
        for (int off = 32; off > 0; off >>= 1) v += __shfl_down(v, off);
        if (lane == 0) lredW[wave][k] = v;
    }
    __syncthreads();

    // per-block normalized contribution: ONE plain store, no atomics, no fences
    if (t == 0) {
        float contrib = 0.f;
        #pragma unroll
        for (int k = 0; k < K; ++k) {
            const float sk = lredW[0][k] + lredW[1][k] + lredW[2][k] + lredW[3][k];
            contrib += sk / cntS[k];
        }
        ws[CTB_OFF + bid] = contrib / (float)K;   // label-mean normalized
    }
}

__global__ __launch_bounds__(TPB)
void pass2_k(const float* __restrict__ bl, const float* __restrict__ il,
             float* __restrict__ ws, int MN) {
    const int bid = blockIdx.x, n4 = MN >> 2;
    const uchar4* lblBase = (const uchar4*)(ws + LBL_OFF);
    if (bid < NBLKB) {
        const int s = bid / BPSB, bx = bid - s * BPSB;
        pass2_slice<2, 2, BPSB>(bl + (size_t)s * 2 * MN, lblBase + (size_t)s * n4,
                                ws, s, bx, bid, n4);
    } else {
        const int r = bid - NBLKB;
        const int si = r / BPSI, bx = r - si * BPSI;
        pass2_slice<6, 5, BPSI>(il + (size_t)si * 5 * MN, lblBase + (size_t)(4 + si) * n4,
                                ws, 4 + si, bx, bid, n4);
    }
}

// ---------------- Final: one wave folds 1536 contributions + 8 scalars ----------------
__global__ void final_k(const float* __restrict__ ws, float* __restrict__ out) {
    const int t = threadIdx.x;   // 64 threads = 1 wave
    float sB = 0.f, sI = 0.f;
    for (int j = t; j < NBLKB; j += 64)        sB += ws[CTB_OFF + j];
    for (int j = NBLKB + t; j < NBLK; j += 64) sI += ws[CTB_OFF + j];
    for (int off = 32; off > 0; off >>= 1) {
        sB += __shfl_down(sB, off);
        sI += __shfl_down(sI, off);
    }
    if (t == 0) {
        float ldrB = 0.f, ldrI = 0.f;
        for (int s = 0; s < 4; ++s) ldrB += ws[LDR_OFF + s];
        for (int s = 4; s < 8; ++s) ldrI += ws[LDR_OFF + s];
        out[0] = 0.25f * (sB + ldrB);
        out[1] = 0.25f * (sI + ldrI);
    }
}

// ---------------- launch: three plain (graph-friendly) dispatches ----------------
extern "C" void kernel_launch(void* const* d_in, const int* in_sizes, int n_in,
                              void* d_out, int out_size, void* d_ws, size_t ws_size,
                              hipStream_t stream) {
    const float* bl = (const float*)d_in[0];
    const int*   bL = (const int*)d_in[1];
    const float* il = (const float*)d_in[2];
    const int*   iL = (const int*)d_in[3];
    float* ws  = (float*)d_ws;
    float* out = (float*)d_out;

    const int B  = 4;
    const int MN = in_sizes[1] / B;   // 524288

    pass1_k<<<dim3(NBLK), dim3(TPB), 0, stream>>>(bl, bL, il, iL, ws, MN);
    pass2_k<<<dim3(NBLK), dim3(TPB), 0, stream>>>(bl, il, ws, MN);
    final_k<<<dim3(1), dim3(64), 0, stream>>>(ws, out);
}

// Round 7
// 135.987 us; speedup vs baseline: 1.0945x; 1.0653x over previous
//
#include <hip/hip_runtime.h>
#include <math.h>

#define DELTA_V 0.5f
#define DELTA_D 3.0f
#define P_REG   0.001f
#define TPB     256
#define NVMAX   36

// Balanced grid: binary 4 iters x 48 B = instance 2 iters x 96 B = 49 KB/block.
// Exact fit at n4 = 131072: 128*256*4 = 256*256*2 = 131072.
#define BPSB 128
#define BPSI 256
#define NBLK (4 * BPSB + 4 * BPSI)   // 1536 blocks = 6/CU, 24 waves/CU

// float-offset ws layout; every word read is written first (poison-safe).
#define P1_OFF    0                             // [NVMAX][NBLK] transposed pass1 partials
#define LBL_OFF   (P1_OFF + NVMAX * NBLK)       // packed uchar labels: 8 * MN bytes = 2*MN floats
#define SCAL_OFF  (LBL_OFF + 2 * 524288)        // [8][8]: cnt[0..5], ldr at +6
#define P2_OFF    (SCAL_OFF + 64)               // [6][NBLK] transposed pass2 partials

__device__ __forceinline__ int slice_base(int s) {
    return (s < 4) ? s * BPSB : 4 * BPSB + (s - 4) * BPSI;
}

// ---------------- Pass 1: per-label counts/sums + label re-pack (math identical to verified r0) ----------------
template<int K, int D>
__device__ void pass1_body(const float* __restrict__ pred,   // [D][MN] this slice
                           const int*  __restrict__ labels,  // [MN]
                           float* __restrict__ ws,
                           uchar4* __restrict__ lblPack,     // [n4] this slice's packed labels
                           int n4, int bx, int stride, int bid,
                           float (*lredW)[NVMAX]) {
    constexpr int NV = K * (D + 1);
    const float4* pred4 = (const float4*)pred;
    const int4*   lab4  = (const int4*)labels;

    float acc[K][D + 1];
    #pragma unroll
    for (int k = 0; k < K; ++k)
        #pragma unroll
        for (int j = 0; j <= D; ++j) acc[k][j] = 0.f;

    for (int i = bx * TPB + threadIdx.x; i < n4; i += stride) {
        int4 lv = lab4[i];
        int labs[4] = {lv.x, lv.y, lv.z, lv.w};
        lblPack[i] = make_uchar4((unsigned char)lv.x, (unsigned char)lv.y,
                                 (unsigned char)lv.z, (unsigned char)lv.w);
        float4 xv[D];
        #pragma unroll
        for (int d = 0; d < D; ++d) xv[d] = pred4[(size_t)d * n4 + i];
        const float* xs = (const float*)&xv[0];   // xs[d*4 + c]
        #pragma unroll
        for (int c = 0; c < 4; ++c) {
            const int lab = labs[c];
            #pragma unroll
            for (int k = 0; k < K; ++k) {
                const float ind = (lab == k) ? 1.f : 0.f;
                acc[k][D] += ind;
                #pragma unroll
                for (int d = 0; d < D; ++d)
                    acc[k][d] = fmaf(ind, xs[d * 4 + c], acc[k][d]);
            }
        }
    }

    const int wave = threadIdx.x >> 6, lane = threadIdx.x & 63;
    #pragma unroll
    for (int k = 0; k < K; ++k) {
        #pragma unroll
        for (int j = 0; j <= D; ++j) {
            float v = acc[k][j];
            for (int off = 32; off > 0; off >>= 1) v += __shfl_down(v, off);
            if (lane == 0) lredW[wave][k * (D + 1) + j] = v;
        }
    }
    __syncthreads();
    if (threadIdx.x < NV) {
        const int t = threadIdx.x;
        ws[P1_OFF + (size_t)t * NBLK + bid] =   // transposed: row t, column bid
            lredW[0][t] + lredW[1][t] + lredW[2][t] + lredW[3][t];
    }
}

__global__ __launch_bounds__(TPB)
void pass1_k(const float* __restrict__ bl, const int* __restrict__ bL,
             const float* __restrict__ il, const int* __restrict__ iL,
             float* __restrict__ ws, int MN) {
    __shared__ float lredW[4][NVMAX];
    const int bid = blockIdx.x, n4 = MN >> 2;
    uchar4* lblBase = (uchar4*)(ws + LBL_OFF);
    if (bid < 4 * BPSB) {
        const int s = bid / BPSB, bx = bid - s * BPSB;
        pass1_body<2, 2>(bl + (size_t)s * 2 * MN, bL + (size_t)s * MN,
                         ws, lblBase + (size_t)s * n4, n4, bx, BPSB * TPB, bid, lredW);
    } else {
        const int r = bid - 4 * BPSB;
        const int si = r / BPSI, bx = r - si * BPSI;
        pass1_body<6, 5>(il + (size_t)si * 5 * MN, iL + (size_t)si * MN,
                         ws, lblBase + (size_t)(4 + si) * n4, n4, bx, BPSI * TPB, bid, lredW);
    }
}

// ---------------- Pass 2: redundant means-reduce + hinged variance (packed labels) ----------------
template<int K, int D, int NBP>
__device__ void pass2_slice(const float* __restrict__ pred,
                            const uchar4* __restrict__ lblPack,
                            float* __restrict__ ws,
                            const int s, const int bx, const int bid, const int n4) {
    constexpr int NV = K * (D + 1);
    __shared__ float tot[NVMAX];
    __shared__ float muS[30];
    __shared__ float cntS[6];
    __shared__ float lredW[4][6];
    const int t = threadIdx.x;
    const int sliceBase = bid - bx;

    // redundant per-block reduce of this slice's transposed partials:
    // thread t streams a CONTIGUOUS row of NBP floats, j ascending ->
    // bitwise-identical means in every block of the slice.
    if (t < NV) {
        const float* P = ws + P1_OFF + (size_t)t * NBLK + sliceBase;
        float v = 0.f;
        #pragma unroll 8
        for (int j = 0; j < NBP; ++j) v += P[j];
        tot[t] = v;
        const int k = t / (D + 1), jj = t - k * (D + 1);
        if (jj == D) cntS[k] = v;
    }
    __syncthreads();
    if (t < NV) {
        const int k = t / (D + 1), jj = t - k * (D + 1);
        if (jj < D) muS[k * D + jj] = tot[t] / cntS[k];
    }
    __syncthreads();

    // block 0 of each slice publishes cnt + (dist + reg) scalar
    if (bx == 0) {
        if (t < K) ws[SCAL_OFF + s * 8 + t] = cntS[t];
        if (t == 0) {
            float l_dist = 0.f, l_reg = 0.f;
            for (int i = 0; i < K; ++i) {
                float n2 = 0.f;
                for (int d = 0; d < D; ++d) n2 += muS[i * D + d] * muS[i * D + d];
                l_reg += sqrtf(n2);
                for (int j = 0; j < K; ++j) {
                    if (i == j) continue;
                    float sq = 0.f;
                    for (int d = 0; d < D; ++d) {
                        const float df = muS[i * D + d] - muS[j * D + d];
                        sq += df * df;
                    }
                    const float dn = fmaxf(2.f * DELTA_D - sqrtf(sq), 0.f);
                    l_dist += dn * dn;
                }
            }
            ws[SCAL_OFF + s * 8 + 6] =
                l_dist / (float)(K * (K - 1)) + P_REG * (l_reg / (float)K);
        }
    }

    // streaming hinged-variance pass: packed 1-byte labels (4 B/quad vs 16 B)
    const float4* pred4 = (const float4*)pred;

    float acc[K];
    #pragma unroll
    for (int k = 0; k < K; ++k) acc[k] = 0.f;

    const int stride = NBP * TPB;
    for (int i = bx * TPB + t; i < n4; i += stride) {
        const uchar4 lq = lblPack[i];
        int labs[4] = {lq.x, lq.y, lq.z, lq.w};
        float4 xv[D];
        #pragma unroll
        for (int d = 0; d < D; ++d) xv[d] = pred4[(size_t)d * n4 + i];
        const float* xs = (const float*)&xv[0];
        #pragma unroll
        for (int c = 0; c < 4; ++c) {
            const int lab = labs[c];
            float sq = 0.f;
            #pragma unroll
            for (int d = 0; d < D; ++d) {
                const float df = muS[lab * D + d] - xs[d * 4 + c];
                sq = fmaf(df, df, sq);
            }
            const float h = fmaxf(sqrtf(sq) - DELTA_V, 0.f);
            const float h2 = h * h;
            #pragma unroll
            for (int k = 0; k < K; ++k)
                acc[k] += (lab == k) ? h2 : 0.f;
        }
    }

    const int wave = t >> 6, lane = t & 63;
    #pragma unroll
    for (int k = 0; k < K; ++k) {
        float v = acc[k];
        for (int off = 32; off > 0; off >>= 1) v += __shfl_down(v, off);
        if (lane == 0) lredW[wave][k] = v;
    }
    __syncthreads();
    if (t < K)
        ws[P2_OFF + (size_t)t * NBLK + bid] =   // transposed: row k, column bid
            lredW[0][t] + lredW[1][t] + lredW[2][t] + lredW[3][t];
}

__global__ __launch_bounds__(TPB)
void pass2_k(const float* __restrict__ bl, const float* __restrict__ il,
             float* __restrict__ ws, int MN) {
    const int bid = blockIdx.x, n4 = MN >> 2;
    const uchar4* lblBase = (const uchar4*)(ws + LBL_OFF);
    if (bid < 4 * BPSB) {
        const int s = bid / BPSB, bx = bid - s * BPSB;
        pass2_slice<2, 2, BPSB>(bl + (size_t)s * 2 * MN, lblBase + (size_t)s * n4,
                                ws, s, bx, bid, n4);
    } else {
        const int r = bid - 4 * BPSB;
        const int si = r / BPSI, bx = r - si * BPSI;
        pass2_slice<6, 5, BPSI>(il + (size_t)si * 5 * MN, lblBase + (size_t)(4 + si) * n4,
                                ws, 4 + si, bx, bid, n4);
    }
}

// ---------------- Final: fold into 2 scalars (contiguous row reads) ----------------
__global__ void final_k(const float* __restrict__ ws, float* __restrict__ out) {
    __shared__ float contrib[48];
    const int t = threadIdx.x;
    if (t < 48) {
        const int s = t / 6, k = t - (t / 6) * 6;
        const int Ks = (s < 4) ? 2 : 6;
        const int NB = (s < 4) ? BPSB : BPSI;
        const int base = slice_base(s);
        float c = 0.f;
        if (k < Ks) {
            const float* P = ws + P2_OFF + (size_t)k * NBLK + base;
            float v = 0.f;
            #pragma unroll 8
            for (int j = 0; j < NB; ++j) v += P[j];
            c = v / ws[SCAL_OFF + s * 8 + k];
        }
        contrib[t] = c;
    }
    __syncthreads();
    if (t == 0) {
        float totB = 0.f, totI = 0.f;
        for (int s = 0; s < 8; ++s) {
            const int Ks = (s < 4) ? 2 : 6;
            float lv = 0.f;
            for (int k = 0; k < Ks; ++k) lv += contrib[s * 6 + k];
            lv /= (float)Ks;
            const float loss = lv + ws[SCAL_OFF + s * 8 + 6];
            if (s < 4) totB += loss; else totI += loss;
        }
        out[0] = totB * 0.25f;
        out[1] = totI * 0.25f;
    }
}

// ---------------- launch: three plain (graph-friendly) dispatches ----------------
extern "C" void kernel_launch(void* const* d_in, const int* in_sizes, int n_in,
                              void* d_out, int out_size, void* d_ws, size_t ws_size,
                              hipStream_t stream) {
    const float* bl = (const float*)d_in[0];
    const int*   bL = (const int*)d_in[1];
    const float* il = (const float*)d_in[2];
    const int*   iL = (const int*)d_in[3];
    float* ws  = (float*)d_ws;
    float* out = (float*)d_out;

    const int B  = 4;
    const int MN = in_sizes[1] / B;   // 524288

    pass1_k<<<dim3(NBLK), dim3(TPB), 0, stream>>>(bl, bL, il, iL, ws, MN);
    pass2_k<<<dim3(NBLK), dim3(TPB), 0, stream>>>(bl, il, ws, MN);
    final_k<<<dim3(1), dim3(64), 0, stream>>>(ws, out);
}